// Round 12
// baseline (621.244 us; speedup 1.0000x reference)
//
#include <hip/hip_runtime.h>
#include <hip/hip_bf16.h>

#define NNODES 20000
#define NEDGES 320000
#define ETOT   (NEDGES + NNODES)   // 340000, self-loops appended after edges
#define KPADX  4224                // 4096 roi + 128 pos (emb1 handled via E1 table)
#define SK     4                   // K-splits for conv1 GEMM
#define KC     (KPADX / SK)        // 1056 = 33*32
#define MPAD   20096               // 157*128
#define NCLS   151
#define EPRW   4808                // 4096 + 512 + 200
#define OUT_LAB_OFF  3020000L      // N*151
#define OUT_EPR_OFF  3040000L      // N*151 + N
#define NSLOPE 0.2f

typedef __attribute__((ext_vector_type(8))) short bf16x8;
typedef __attribute__((ext_vector_type(4))) float f32x4;
typedef __attribute__((ext_vector_type(4))) short s16x4;

__device__ __forceinline__ short f2bf(float v) {
  union { __hip_bfloat16 b; short s; } u;
  u.b = __float2bfloat16(v);
  return u.s;
}

__device__ __forceinline__ float bf2f(short s) {
  union { float f; unsigned u; } x;
  x.u = ((unsigned)(unsigned short)s) << 16;
  return x.f;
}

__device__ __forceinline__ void gld16(const short* g, short* l) {
  __builtin_amdgcn_global_load_lds(
      (const __attribute__((address_space(1))) unsigned int*)g,
      (__attribute__((address_space(3))) unsigned int*)l, 16, 0, 0);
}

// ---------------------------------------------------------------------------
// mega-prep block ranges (separate ranges per stream):
//  [0, 5000)     X CONVERT: roi -> x bf16 NT (16B bf16x8 stores, no barriers)
//  [.., +10000)  EPR COPY: roi -> epr f32 NT (16B stores, no barriers)
//  [.., +5000)   MLP/emb2/one-hot/label: 4 nodes/block, 1 wave/node
//  [.., +1584)   zero init: x/ef1 pad rows, als2/ald2
//  [.., +2112)   transpose W1 -> w1t bf16 [512][4224] (skip emb1 rows)
//  [.., +256)    transpose W2 -> w2t bf16 [512][512]
//  [.., +1329)   deg_count (deg pre-zeroed via hipMemsetAsync)
//  [.., +151)    E1[c] = emb1[c] @ W1b (f32 [151][512])
// ---------------------------------------------------------------------------
#define QB0  5000
#define QB0b (QB0 + 10000)
#define QB1  (QB0b + 5000)
#define QB2  (QB1 + 1584)
#define QB3  (QB2 + 2112)
#define QB4  (QB3 + 256)
#define QB5  (QB4 + 1329)
#define QB6  (QB5 + 151)

__global__ __launch_bounds__(256) void mega_prep_kernel(
    const float* __restrict__ roi, const float* __restrict__ box,
    const float* __restrict__ emb1, const float* __restrict__ emb2,
    const float* __restrict__ bw1, const float* __restrict__ bb1,
    const float* __restrict__ bw2, const float* __restrict__ bb2,
    const float* __restrict__ W1, const float* __restrict__ W2,
    const int* __restrict__ labels, const int* __restrict__ ei,
    short* __restrict__ x, short* __restrict__ w1t, short* __restrict__ w2t,
    short* __restrict__ ef1, int* __restrict__ deg,
    float* __restrict__ als2, float* __restrict__ ald2,
    float* __restrict__ E1, float* __restrict__ dout) {
  const int b = blockIdx.x;
  const int tid = threadIdx.x;

  __shared__ float hids[4][32];
  __shared__ float tile[32][33];

  if (b < QB0) {
    // ---- x convert: chunk = 8 floats -> one 16B bf16x8 NT store ----
    const int c0 = b * 2048 + tid;
    f32x4 v0[8], v1[8];
#pragma unroll
    for (int k = 0; k < 8; ++k) {
      const int c = c0 + k * 256;
      const float* src = &roi[((long)(c >> 9) << 12) + (c & 511) * 8];
      v0[k] = *(const f32x4*)src;
      v1[k] = *(const f32x4*)(src + 4);
    }
#pragma unroll
    for (int k = 0; k < 8; ++k) {
      const int c = c0 + k * 256;
      bf16x8 bb;
      bb[0] = f2bf(v0[k].x); bb[1] = f2bf(v0[k].y);
      bb[2] = f2bf(v0[k].z); bb[3] = f2bf(v0[k].w);
      bb[4] = f2bf(v1[k].x); bb[5] = f2bf(v1[k].y);
      bb[6] = f2bf(v1[k].z); bb[7] = f2bf(v1[k].w);
      __builtin_nontemporal_store(bb,
          (bf16x8*)&x[(long)(c >> 9) * KPADX + (c & 511) * 8]);
    }
  } else if (b < QB0b) {
    // ---- epr roi-copy: chunk = 4 floats (16B) ----
    const int t = b - QB0;
    const int c0 = t * 2048 + tid;
    f32x4 v[8];
#pragma unroll
    for (int k = 0; k < 8; ++k) {
      const int c = c0 + k * 256;
      v[k] = *(const f32x4*)&roi[((long)(c >> 10) << 12) + (c & 1023) * 4];
    }
#pragma unroll
    for (int k = 0; k < 8; ++k) {
      const int c = c0 + k * 256;
      __builtin_nontemporal_store(v[k],
          (f32x4*)&dout[OUT_EPR_OFF + (long)(c >> 10) * EPRW + (c & 1023) * 4]);
    }
  } else if (b < QB1) {
    // ---- MLP + emb2 + one-hot + label: 4 nodes/block, wave per node ----
    const int w = tid >> 6;
    const int lane = tid & 63;
    const int nd = (b - QB0b) * 4 + w;
    if (lane < 32) {
      float a = bb1[lane];
#pragma unroll
      for (int i = 0; i < 9; ++i) a += box[nd * 9 + i] * bw1[i * 32 + lane];
      hids[w][lane] = a > 0.f ? a : 0.f;
    }
    __syncthreads();
    const long xrow = (long)nd * KPADX;
#pragma unroll
    for (int jj = 0; jj < 2; ++jj) {
      const int j = lane + jj * 64;
      float a = bb2[j];
#pragma unroll
      for (int i = 0; i < 32; ++i) a += hids[w][i] * bw2[i * 128 + j];
      a = a > 0.f ? a : 0.f;
      x[xrow + 4096 + j] = f2bf(a);      // pos (x cols 4096..4223)
    }
    const int lab = labels[nd];
    float* epr = dout + OUT_EPR_OFF + (long)nd * EPRW;
    if (lane < 50) {
      const f32x4 e2 = *(const f32x4*)&emb2[lab * 200 + lane * 4];
      __builtin_nontemporal_store(e2, (f32x4*)&epr[4608 + lane * 4]);
    }
    for (int j = lane; j < NCLS; j += 64)
      dout[(long)nd * NCLS + j] = (j == lab) ? 1.f : 0.f;
    if (lane == 0) dout[OUT_LAB_OFF + nd] = (float)lab;
  } else if (b < QB2) {
    // ---- zero init ----
    const int t = (b - QB1) * 256 + tid;
    if (t < 96 * KPADX) x[(long)NNODES * KPADX + t] = 0;
    if (t < 96 * 512)   ef1[(long)NNODES * 512 + t] = 0;
    if (t < MPAD)       { als2[t] = 0.f; ald2[t] = 0.f; }
  } else if (b < QB3) {
    // ---- transpose W1 (4424x512 -> [512][4224], skipping emb rows) ----
    const int t = b - QB2;
    const int n0 = (t % 16) * 32;
    const int k0 = (t / 16) * 32;
    const int tx = tid & 31, ty = tid >> 5;
#pragma unroll
    for (int i = ty; i < 32; i += 8) {
      const int kp = k0 + i;
      const int src = kp < 4096 ? kp : kp + 200;
      tile[i][tx] = W1[(long)src * 512 + (n0 + tx)];
    }
    __syncthreads();
#pragma unroll
    for (int i = ty; i < 32; i += 8)
      w1t[(long)(n0 + i) * KPADX + (k0 + tx)] = f2bf(tile[tx][i]);
  } else if (b < QB4) {
    // ---- transpose W2 (512x512) ----
    const int t = b - QB3;
    const int n0 = (t % 16) * 32;
    const int k0 = (t / 16) * 32;
    const int tx = tid & 31, ty = tid >> 5;
#pragma unroll
    for (int i = ty; i < 32; i += 8)
      tile[i][tx] = W2[(long)(k0 + i) * 512 + (n0 + tx)];
    __syncthreads();
#pragma unroll
    for (int i = ty; i < 32; i += 8)
      w2t[(long)(n0 + i) * 512 + (k0 + tx)] = f2bf(tile[tx][i]);
  } else if (b < QB5) {
    // ---- deg_count ----
    const int e = (b - QB4) * 256 + tid;
    if (e < ETOT) {
      const int d = (e < NEDGES) ? ei[NEDGES + e] : (e - NEDGES);
      atomicAdd(&deg[d], 1);
    }
  } else {
    // ---- E1 = emb1 @ W1b ([151][512] f32) ----
    const int c = b - QB5;
#pragma unroll
    for (int jj = 0; jj < 2; ++jj) {
      const int j = tid + jj * 256;
      float a = 0.f;
      for (int k = 0; k < 200; ++k)
        a += emb1[c * 200 + k] * W1[(long)(4096 + k) * 512 + j];
      E1[c * 512 + j] = a;
    }
  }
}

// ---------------------------------------------------------------------------
// single-block exclusive scan over 20000 degrees -> off, cursor
// ---------------------------------------------------------------------------
__global__ __launch_bounds__(256) void scan_kernel(const int* __restrict__ deg,
                                                   int* __restrict__ off,
                                                   int* __restrict__ cur) {
  __shared__ int part[256];
  const int tid = threadIdx.x;
  const int chunk = (NNODES + 255) / 256;
  int start = tid * chunk;
  int end = start + chunk; if (end > NNODES) end = NNODES;
  int s = 0;
  for (int i = start; i < end; ++i) s += deg[i];
  part[tid] = s;
  __syncthreads();
  for (int d = 1; d < 256; d <<= 1) {
    const int v = (tid >= d) ? part[tid - d] : 0;
    __syncthreads();
    part[tid] += v;
    __syncthreads();
  }
  int base = part[tid] - s;   // exclusive base of this thread's chunk
  for (int i = start; i < end; ++i) { off[i] = base; cur[i] = base; base += deg[i]; }
}

__global__ void csr_fill_kernel(const int* __restrict__ ei, int* __restrict__ cur,
                                int* __restrict__ csrs) {
  const int e = blockIdx.x * 256 + threadIdx.x;
  if (e >= ETOT) return;
  const int s = (e < NEDGES) ? ei[e] : (e - NEDGES);
  const int d = (e < NEDGES) ? ei[NEDGES + e] : (e - NEDGES);
  unsigned slot = (unsigned)atomicAdd(&cur[d], 1);
  if (slot >= ETOT) slot = 0;   // hardening; never hit when deg is correct
  csrs[slot] = s;
}

// ---------------------------------------------------------------------------
// Split-K conv1 GEMM, DOUBLE-BUFFERED with counted vmcnt (T4 pattern):
// stage tile t+1 into buf^1, wait vmcnt(4) (only tile t's loads), raw
// s_barrier (no compiler vmcnt(0) drain) -> next-tile loads stay in flight.
// 2512 blocks = 157 bm x 4 sk x 4 bn, XCD-grouped decode (2512 = 8*314).
// ---------------------------------------------------------------------------
__global__ __launch_bounds__(256) void gemm_split(const short* __restrict__ A,
                                                  const short* __restrict__ BT,
                                                  short* __restrict__ hp) {
  __shared__ short As[2][4096];   // [buf][128 rows][32 k]
  __shared__ short Bs[2][4096];
  const int tid = threadIdx.x;
  const int lane = tid & 63;
  const int w = tid >> 6;
  const int wr = w >> 1, wc = w & 1;
  const int wid = (blockIdx.x & 7) * 314 + ((int)blockIdx.x >> 3);
  const long bm = (long)(wid >> 4) * 128;
  const int  sk = (wid >> 2) & 3;
  const long bn = (long)(wid & 3) * 128;

  f32x4 acc[4][4] = {};

  const short* gA0 = A + (bm + w * 32 + (lane >> 2)) * (long)KPADX + sk * KC + (lane & 3) * 8;
  const short* gA1 = gA0 + 16L * KPADX;
  const short* gB0 = BT + (bn + w * 32 + (lane >> 2)) * (long)KPADX + sk * KC + (lane & 3) * 8;
  const short* gB1 = gB0 + 16L * KPADX;

  const int lofs = w * 1024;
  const int ar = (wr * 64 + (lane & 15)) * 32 + (lane >> 4) * 8;
  const int br = (wc * 64 + (lane & 15)) * 32 + (lane >> 4) * 8;

  // prologue: stage tile 0 into buf 0
  gld16(gA0, &As[0][lofs]); gld16(gA1, &As[0][lofs + 512]);
  gld16(gB0, &Bs[0][lofs]); gld16(gB1, &Bs[0][lofs + 512]);
  gA0 += 32; gA1 += 32; gB0 += 32; gB1 += 32;

  const int NT = KC / 32;   // 33
  int cur = 0;
  for (int t = 0; t < NT; ++t) {
    if (t + 1 < NT) {
      gld16(gA0, &As[cur ^ 1][lofs]); gld16(gA1, &As[cur ^ 1][lofs + 512]);
      gld16(gB0, &Bs[cur ^ 1][lofs]); gld16(gB1, &Bs[cur ^ 1][lofs + 512]);
      gA0 += 32; gA1 += 32; gB0 += 32; gB1 += 32;
      asm volatile("s_waitcnt vmcnt(4)" ::: "memory");
    } else {
      asm volatile("s_waitcnt vmcnt(0)" ::: "memory");
    }
    __builtin_amdgcn_s_barrier();
    bf16x8 a[4], b[4];
#pragma unroll
    for (int mi = 0; mi < 4; ++mi) a[mi] = *(const bf16x8*)&As[cur][ar + mi * 512];
#pragma unroll
    for (int ni = 0; ni < 4; ++ni) b[ni] = *(const bf16x8*)&Bs[cur][br + ni * 512];
#pragma unroll
    for (int mi = 0; mi < 4; ++mi)
#pragma unroll
      for (int ni = 0; ni < 4; ++ni)
        acc[mi][ni] = __builtin_amdgcn_mfma_f32_16x16x32_bf16(a[mi], b[ni], acc[mi][ni], 0, 0, 0);
    __builtin_amdgcn_s_barrier();
    cur ^= 1;
  }

  short* Cp = hp + (long)sk * MPAD * 512;
#pragma unroll
  for (int mi = 0; mi < 4; ++mi) {
#pragma unroll
    for (int ni = 0; ni < 4; ++ni) {
      const long row0 = bm + wr * 64 + mi * 16 + (lane >> 4) * 4;
      const long col  = bn + wc * 64 + ni * 16 + (lane & 15);
#pragma unroll
      for (int r = 0; r < 4; ++r)
        Cp[(row0 + r) * 512 + col] = f2bf(acc[mi][ni][r]);
    }
  }
}

// ---------------------------------------------------------------------------
// reduce1: h1 = sum(hp[0..3]) + E1[label]; als/ald direct store.
// One wave per row, 4 rows/block. h1 aliases hp[0] (in-place, read-first).
// ---------------------------------------------------------------------------
__global__ __launch_bounds__(256) void reduce1_kernel(short* __restrict__ hp,
    const float* __restrict__ E1, const int* __restrict__ labels,
    const float* __restrict__ aS, const float* __restrict__ aD,
    float* __restrict__ als, float* __restrict__ ald) {
  const int row = blockIdx.x * 4 + (threadIdx.x >> 6);
  const int lane = threadIdx.x & 63;
  const int c0 = lane * 8;
  const long base = (long)row * 512 + c0;
  float v[8] = {};
#pragma unroll
  for (int s = 0; s < SK; ++s) {
    const bf16x8 p = *(const bf16x8*)&hp[(long)s * MPAD * 512 + base];
#pragma unroll
    for (int j = 0; j < 8; ++j) v[j] += bf2f(p[j]);
  }
  const int lab = (row < NNODES) ? labels[row] : 0;
  const float* e1r = E1 + (long)lab * 512;
#pragma unroll
  for (int j = 0; j < 8; ++j) v[j] += e1r[c0 + j];
  bf16x8 o;
#pragma unroll
  for (int j = 0; j < 8; ++j) o[j] = f2bf(v[j]);
  *(bf16x8*)&hp[base] = o;   // h1 = hp chunk 0 (in-place)
  float s_ = 0.f, d_ = 0.f;
#pragma unroll
  for (int j = 0; j < 8; ++j) {
    s_ += v[j] * aS[c0 + j];
    d_ += v[j] * aD[c0 + j];
  }
#pragma unroll
  for (int oo = 1; oo < 8; oo <<= 1) {
    s_ += __shfl_xor(s_, oo);
    d_ += __shfl_xor(d_, oo);
  }
  if ((lane & 7) == 0) {
    const int head = lane >> 3;
    als[row * 8 + head] = s_;
    ald[row * 8 + head] = d_;
  }
}

// ---------------------------------------------------------------------------
// conv2 GEMM, double-buffered like gemm_split; fused als/ald epilogue.
// ---------------------------------------------------------------------------
__global__ __launch_bounds__(256) void gemm_bt(const short* __restrict__ A,
                                               const short* __restrict__ BT,
                                               short* __restrict__ C,
                                               const float* __restrict__ aS,
                                               const float* __restrict__ aD,
                                               float* __restrict__ als,
                                               float* __restrict__ ald,
                                               int Kpad, int Ncols, int H) {
  __shared__ short As[2][4096];
  __shared__ short Bs[2][4096];
  const int tid = threadIdx.x;
  const int lane = tid & 63;
  const int w = tid >> 6;
  const int wr = w >> 1, wc = w & 1;
  const int nbn = Ncols >> 7;
  const long bm = (long)((int)blockIdx.x / nbn) * 128;
  const long bn = (long)((int)blockIdx.x % nbn) * 128;

  f32x4 acc[4][4] = {};

  const short* gA0 = A + (bm + w * 32 + (lane >> 2)) * (long)Kpad + (lane & 3) * 8;
  const short* gA1 = gA0 + 16L * Kpad;
  const short* gB0 = BT + (bn + w * 32 + (lane >> 2)) * (long)Kpad + (lane & 3) * 8;
  const short* gB1 = gB0 + 16L * Kpad;

  const int lofs = w * 1024;
  const int ar = (wr * 64 + (lane & 15)) * 32 + (lane >> 4) * 8;
  const int br = (wc * 64 + (lane & 15)) * 32 + (lane >> 4) * 8;

  gld16(gA0, &As[0][lofs]); gld16(gA1, &As[0][lofs + 512]);
  gld16(gB0, &Bs[0][lofs]); gld16(gB1, &Bs[0][lofs + 512]);
  gA0 += 32; gA1 += 32; gB0 += 32; gB1 += 32;

  const int NT = Kpad / 32;
  int cur = 0;
  for (int t = 0; t < NT; ++t) {
    if (t + 1 < NT) {
      gld16(gA0, &As[cur ^ 1][lofs]); gld16(gA1, &As[cur ^ 1][lofs + 512]);
      gld16(gB0, &Bs[cur ^ 1][lofs]); gld16(gB1, &Bs[cur ^ 1][lofs + 512]);
      gA0 += 32; gA1 += 32; gB0 += 32; gB1 += 32;
      asm volatile("s_waitcnt vmcnt(4)" ::: "memory");
    } else {
      asm volatile("s_waitcnt vmcnt(0)" ::: "memory");
    }
    __builtin_amdgcn_s_barrier();
    bf16x8 a[4], b[4];
#pragma unroll
    for (int mi = 0; mi < 4; ++mi) a[mi] = *(const bf16x8*)&As[cur][ar + mi * 512];
#pragma unroll
    for (int ni = 0; ni < 4; ++ni) b[ni] = *(const bf16x8*)&Bs[cur][br + ni * 512];
#pragma unroll
    for (int mi = 0; mi < 4; ++mi)
#pragma unroll
      for (int ni = 0; ni < 4; ++ni)
        acc[mi][ni] = __builtin_amdgcn_mfma_f32_16x16x32_bf16(a[mi], b[ni], acc[mi][ni], 0, 0, 0);
    __builtin_amdgcn_s_barrier();
    cur ^= 1;
  }

  const int colb = (int)bn + wc * 64 + (lane & 15);

#pragma unroll
  for (int mi = 0; mi < 4; ++mi) {
#pragma unroll
    for (int ni = 0; ni < 4; ++ni) {
      const long row0 = bm + wr * 64 + mi * 16 + (lane >> 4) * 4;
      const long col  = bn + wc * 64 + ni * 16 + (lane & 15);
#pragma unroll
      for (int r = 0; r < 4; ++r)
        C[(row0 + r) * (long)Ncols + col] = f2bf(acc[mi][ni][r]);
    }
  }

  float asv[4], adv[4];
#pragma unroll
  for (int ni = 0; ni < 4; ++ni) {
    asv[ni] = aS[colb + ni * 16];
    adv[ni] = aD[colb + ni * 16];
  }
  const int head = (H == 8) ? (((int)bn >> 6) + wc) : 0;
#pragma unroll
  for (int mi = 0; mi < 4; ++mi) {
#pragma unroll
    for (int r = 0; r < 4; ++r) {
      float s = 0.f, d = 0.f;
#pragma unroll
      for (int ni = 0; ni < 4; ++ni) {
        const float v = acc[mi][ni][r];
        s += v * asv[ni];
        d += v * adv[ni];
      }
#pragma unroll
      for (int o = 1; o < 16; o <<= 1) {
        s += __shfl_xor(s, o);
        d += __shfl_xor(d, o);
      }
      if ((lane & 15) == 0) {
        const long row = bm + wr * 64 + mi * 16 + (lane >> 4) * 4 + r;
        atomicAdd(&als[row * H + head], s);
        atomicAdd(&ald[row * H + head], d);
      }
    }
  }
}

// ---------------------------------------------------------------------------
// fused per-node softmax + gather kernels
// ---------------------------------------------------------------------------
__global__ __launch_bounds__(256) void gather1_kernel(const int* __restrict__ off,
    const int* __restrict__ csrs,
    const float* __restrict__ als, const float* __restrict__ ald,
    const short* __restrict__ h1, const float* __restrict__ bias,
    short* __restrict__ ef1) {
  const int dn = blockIdx.x * 4 + (threadIdx.x >> 6);
  const int lane = threadIdx.x & 63;
  const int c0 = lane * 8;
  const int head = lane >> 3;
  const int beg = off[dn];
  const int end = (dn == NNODES - 1) ? ETOT : off[dn + 1];
  const float ad = ald[dn * 8 + head];
  float sum = 0.f;
  float acc[8] = {};
  for (int i = beg; i < end; ++i) {
    int s = csrs[i];
    if ((unsigned)s >= NNODES) s = 0;   // hardening
    float l = als[s * 8 + head] + ad;
    l = l > 0.f ? l : NSLOPE * l;
    const float wgt = expf(l);
    sum += wgt;
    const bf16x8 hv = *(const bf16x8*)&h1[(long)s * 512 + c0];
#pragma unroll
    for (int j = 0; j < 8; ++j) acc[j] += wgt * bf2f(hv[j]);
  }
  const float inv = 1.f / (sum + 1e-16f);
  bf16x8 outv;
#pragma unroll
  for (int j = 0; j < 8; ++j) {
    float r = acc[j] * inv + bias[c0 + j];
    r = r > 0.f ? r : expm1f(r);   // elu
    outv[j] = f2bf(r);
  }
  *(bf16x8*)&ef1[(long)dn * 512 + c0] = outv;
}

__global__ __launch_bounds__(256) void gather2_kernel(const int* __restrict__ off,
    const int* __restrict__ csrs,
    const float* __restrict__ als, const float* __restrict__ ald,
    const short* __restrict__ h2, const float* __restrict__ bias,
    float* __restrict__ dout) {
  const int dn = blockIdx.x * 4 + (threadIdx.x >> 6);
  const int lane = threadIdx.x & 63;
  const int c0 = lane * 8;
  const int beg = off[dn];
  const int end = (dn == NNODES - 1) ? ETOT : off[dn + 1];
  const float ad = ald[dn];
  float sum = 0.f;
  float acc[8] = {};
  for (int i = beg; i < end; ++i) {
    int s = csrs[i];
    if ((unsigned)s >= NNODES) s = 0;   // hardening
    float l = als[s] + ad;
    l = l > 0.f ? l : NSLOPE * l;
    const float wgt = expf(l);
    sum += wgt;
    const bf16x8 hv = *(const bf16x8*)&h2[(long)s * 512 + c0];
#pragma unroll
    for (int j = 0; j < 8; ++j) acc[j] += wgt * bf2f(hv[j]);
  }
  const float inv = 1.f / (sum + 1e-16f);
  float* epr = dout + OUT_EPR_OFF + (long)dn * EPRW + 4096;
  f32x4 o0, o1;
  o0.x = acc[0] * inv + bias[c0 + 0];
  o0.y = acc[1] * inv + bias[c0 + 1];
  o0.z = acc[2] * inv + bias[c0 + 2];
  o0.w = acc[3] * inv + bias[c0 + 3];
  o1.x = acc[4] * inv + bias[c0 + 4];
  o1.y = acc[5] * inv + bias[c0 + 5];
  o1.z = acc[6] * inv + bias[c0 + 6];
  o1.w = acc[7] * inv + bias[c0 + 7];
  __builtin_nontemporal_store(o0, (f32x4*)&epr[c0]);
  __builtin_nontemporal_store(o1, (f32x4*)&epr[c0 + 4]);
}

// ---------------------------------------------------------------------------
extern "C" void kernel_launch(void* const* d_in, const int* in_sizes, int n_in,
                              void* d_out, int out_size, void* d_ws, size_t ws_size,
                              hipStream_t stream) {
  const float* roi  = (const float*)d_in[0];
  const float* box  = (const float*)d_in[1];
  const float* emb1 = (const float*)d_in[2];
  const float* emb2 = (const float*)d_in[3];
  const float* bw1  = (const float*)d_in[4];
  const float* bb1  = (const float*)d_in[5];
  const float* bw2  = (const float*)d_in[6];
  const float* bb2  = (const float*)d_in[7];
  const float* W1   = (const float*)d_in[8];
  const float* as1  = (const float*)d_in[9];
  const float* ad1  = (const float*)d_in[10];
  const float* b1   = (const float*)d_in[11];
  const float* W2   = (const float*)d_in[12];
  const float* as2  = (const float*)d_in[13];
  const float* ad2  = (const float*)d_in[14];
  const float* b2   = (const float*)d_in[15];
  const int* labels = (const int*)d_in[16];
  const int* ei     = (const int*)d_in[17];
  float* dout = (float*)d_out;

  char* wsb = (char*)d_ws;
  size_t o = 0;
  auto alloc = [&](size_t bytes) -> void* {
    void* p = wsb + o;
    o += (bytes + 255) & ~(size_t)255;
    return p;
  };
  short* x    = (short*)alloc((size_t)MPAD * KPADX * 2);       // bf16 [MPAD][4224]
  short* w1t  = (short*)alloc((size_t)512 * KPADX * 2);        // bf16 [512][4224]
  short* hp   = (short*)alloc((size_t)SK * MPAD * 512 * 2);    // bf16 partials; h1 = chunk 0
  short* h1   = hp;
  short* ef1  = (short*)alloc((size_t)MPAD * 512 * 2);         // bf16
  short* w2t  = (short*)alloc((size_t)512 * 512 * 2);
  short* h2   = (short*)alloc((size_t)MPAD * 512 * 2);         // bf16
  float* als1 = (float*)alloc((size_t)MPAD * 8 * 4);
  float* ald1 = (float*)alloc((size_t)MPAD * 8 * 4);
  float* als2 = (float*)alloc((size_t)MPAD * 4);
  float* ald2 = (float*)alloc((size_t)MPAD * 4);
  float* E1   = (float*)alloc((size_t)NCLS * 512 * 4);
  int*   deg  = (int*)alloc((size_t)NNODES * 4);
  int*   offs = (int*)alloc((size_t)NNODES * 4);
  int*   cur  = (int*)alloc((size_t)NNODES * 4);
  int*   csrs = (int*)alloc((size_t)ETOT * 4);

  const int EB = (ETOT + 255) / 256;   // 1329

  hipMemsetAsync(deg, 0, (size_t)NNODES * 4, stream);

  hipLaunchKernelGGL(mega_prep_kernel, dim3(QB6), dim3(256), 0, stream,
                     roi, box, emb1, emb2, bw1, bb1, bw2, bb2, W1, W2,
                     labels, ei, x, w1t, w2t, ef1, deg,
                     als2, ald2, E1, dout);
  hipLaunchKernelGGL(scan_kernel, dim3(1), dim3(256), 0, stream, deg, offs, cur);
  hipLaunchKernelGGL(csr_fill_kernel, dim3(EB), dim3(256), 0, stream, ei, cur, csrs);
  // conv1: split-K GEMM -> partials, then reduce (+E1, +als/ald)
  hipLaunchKernelGGL(gemm_split, dim3(157 * SK * 4), dim3(256), 0, stream,
                     x, w1t, hp);
  hipLaunchKernelGGL(reduce1_kernel, dim3(MPAD / 4), dim3(256), 0, stream,
                     hp, E1, labels, as1, ad1, als1, ald1);
  hipLaunchKernelGGL(gather1_kernel, dim3(NNODES / 4), dim3(256), 0, stream,
                     offs, csrs, als1, ald1, h1, b1, ef1);
  // conv2 GEMM (+fused als/ald)
  hipLaunchKernelGGL(gemm_bt, dim3(157 * 4), dim3(256), 0, stream,
                     ef1, w2t, h2, as2, ad2, als2, ald2, 512, 512, 1);
  hipLaunchKernelGGL(gather2_kernel, dim3(NNODES / 4), dim3(256), 0, stream,
                     offs, csrs, als2, ald2, h2, b2, dout);
}

// Round 13
// 577.602 us; speedup vs baseline: 1.0756x; 1.0756x over previous
//
#include <hip/hip_runtime.h>
#include <hip/hip_bf16.h>

#define NNODES 20000
#define NEDGES 320000
#define ETOT   (NEDGES + NNODES)   // 340000, self-loops appended after edges
#define KPADX  4224                // 4096 roi + 128 pos (emb1 handled via E1 table)
#define SK     4                   // K-splits for conv1 GEMM
#define KC     (KPADX / SK)        // 1056 = 33*32
#define MPAD   20096               // 157*128
#define NCLS   151
#define EPRW   4808                // 4096 + 512 + 200
#define OUT_LAB_OFF  3020000L      // N*151
#define OUT_EPR_OFF  3040000L      // N*151 + N
#define NSLOPE 0.2f

typedef __attribute__((ext_vector_type(8))) short bf16x8;
typedef __attribute__((ext_vector_type(4))) float f32x4;
typedef __attribute__((ext_vector_type(4))) short s16x4;

__device__ __forceinline__ short f2bf(float v) {
  union { __hip_bfloat16 b; short s; } u;
  u.b = __float2bfloat16(v);
  return u.s;
}

__device__ __forceinline__ float bf2f(short s) {
  union { float f; unsigned u; } x;
  x.u = ((unsigned)(unsigned short)s) << 16;
  return x.f;
}

__device__ __forceinline__ void gld16(const short* g, short* l) {
  __builtin_amdgcn_global_load_lds(
      (const __attribute__((address_space(1))) unsigned int*)g,
      (__attribute__((address_space(3))) unsigned int*)l, 16, 0, 0);
}

// ---------------------------------------------------------------------------
// mega-prep block ranges (r10-proven structure: single roi read, dual store):
//  [0, 10000)   ROI COPY: roi -> epr (f32 NT) + x (bf16), 8 indep 16B chunks/thr
//  [.., +5000)  MLP/emb2/one-hot/label: 4 nodes/block, 1 wave/node
//  [.., +1584)  zero init: x/ef1 pad rows, als2/ald2
//  [.., +2112)  transpose W1 -> w1t bf16 [512][4224] (skip emb1 rows)
//  [.., +256)   transpose W2 -> w2t bf16 [512][512]
//  [.., +1329)  deg_count (deg pre-zeroed via hipMemsetAsync)
//  [.., +151)   E1[c] = emb1[c] @ W1b (f32 [151][512])
// ---------------------------------------------------------------------------
#define QB0 10000
#define QB1 (QB0 + 5000)
#define QB2 (QB1 + 1584)
#define QB3 (QB2 + 2112)
#define QB4 (QB3 + 256)
#define QB5 (QB4 + 1329)
#define QB6 (QB5 + 151)

__global__ __launch_bounds__(256) void mega_prep_kernel(
    const float* __restrict__ roi, const float* __restrict__ box,
    const float* __restrict__ emb1, const float* __restrict__ emb2,
    const float* __restrict__ bw1, const float* __restrict__ bb1,
    const float* __restrict__ bw2, const float* __restrict__ bb2,
    const float* __restrict__ W1, const float* __restrict__ W2,
    const int* __restrict__ labels, const int* __restrict__ ei,
    short* __restrict__ x, short* __restrict__ w1t, short* __restrict__ w2t,
    short* __restrict__ ef1, int* __restrict__ deg,
    float* __restrict__ als2, float* __restrict__ ald2,
    float* __restrict__ E1, float* __restrict__ dout) {
  const int b = blockIdx.x;
  const int tid = threadIdx.x;

  __shared__ float hids[4][32];
  __shared__ float tile[32][33];

  if (b < QB0) {
    // ---- roi streaming copy: 2048 chunks/block, 8/thread, no barriers ----
    const int base = b * 2048 + tid;
    f32x4 v[8];
#pragma unroll
    for (int k = 0; k < 8; ++k)
      v[k] = *(const f32x4*)&roi[(long)(base + k * 256) * 4];
#pragma unroll
    for (int k = 0; k < 8; ++k) {
      const int t = base + k * 256;
      const int node = t >> 10, cq = t & 1023;
      __builtin_nontemporal_store(v[k],
          (f32x4*)&dout[OUT_EPR_OFF + (long)node * EPRW + cq * 4]);
      s16x4 bb;
      bb.x = f2bf(v[k].x); bb.y = f2bf(v[k].y);
      bb.z = f2bf(v[k].z); bb.w = f2bf(v[k].w);
      *(s16x4*)&x[(long)node * KPADX + cq * 4] = bb;
    }
  } else if (b < QB1) {
    // ---- MLP + emb2 + one-hot + label: 4 nodes/block, wave per node ----
    const int w = tid >> 6;
    const int lane = tid & 63;
    const int nd = (b - QB0) * 4 + w;
    if (lane < 32) {
      float a = bb1[lane];
#pragma unroll
      for (int i = 0; i < 9; ++i) a += box[nd * 9 + i] * bw1[i * 32 + lane];
      hids[w][lane] = a > 0.f ? a : 0.f;
    }
    __syncthreads();
    const long xrow = (long)nd * KPADX;
#pragma unroll
    for (int jj = 0; jj < 2; ++jj) {
      const int j = lane + jj * 64;
      float a = bb2[j];
#pragma unroll
      for (int i = 0; i < 32; ++i) a += hids[w][i] * bw2[i * 128 + j];
      a = a > 0.f ? a : 0.f;
      x[xrow + 4096 + j] = f2bf(a);      // pos (x cols 4096..4223)
    }
    const int lab = labels[nd];
    float* epr = dout + OUT_EPR_OFF + (long)nd * EPRW;
    if (lane < 50) {
      const f32x4 e2 = *(const f32x4*)&emb2[lab * 200 + lane * 4];
      __builtin_nontemporal_store(e2, (f32x4*)&epr[4608 + lane * 4]);
    }
    for (int j = lane; j < NCLS; j += 64)
      dout[(long)nd * NCLS + j] = (j == lab) ? 1.f : 0.f;
    if (lane == 0) dout[OUT_LAB_OFF + nd] = (float)lab;
  } else if (b < QB2) {
    // ---- zero init ----
    const int t = (b - QB1) * 256 + tid;
    if (t < 96 * KPADX) x[(long)NNODES * KPADX + t] = 0;
    if (t < 96 * 512)   ef1[(long)NNODES * 512 + t] = 0;
    if (t < MPAD)       { als2[t] = 0.f; ald2[t] = 0.f; }
  } else if (b < QB3) {
    // ---- transpose W1 (4424x512 -> [512][4224], skipping emb rows) ----
    const int t = b - QB2;
    const int n0 = (t % 16) * 32;
    const int k0 = (t / 16) * 32;
    const int tx = tid & 31, ty = tid >> 5;
#pragma unroll
    for (int i = ty; i < 32; i += 8) {
      const int kp = k0 + i;
      const int src = kp < 4096 ? kp : kp + 200;
      tile[i][tx] = W1[(long)src * 512 + (n0 + tx)];
    }
    __syncthreads();
#pragma unroll
    for (int i = ty; i < 32; i += 8)
      w1t[(long)(n0 + i) * KPADX + (k0 + tx)] = f2bf(tile[tx][i]);
  } else if (b < QB4) {
    // ---- transpose W2 (512x512) ----
    const int t = b - QB3;
    const int n0 = (t % 16) * 32;
    const int k0 = (t / 16) * 32;
    const int tx = tid & 31, ty = tid >> 5;
#pragma unroll
    for (int i = ty; i < 32; i += 8)
      tile[i][tx] = W2[(long)(k0 + i) * 512 + (n0 + tx)];
    __syncthreads();
#pragma unroll
    for (int i = ty; i < 32; i += 8)
      w2t[(long)(n0 + i) * 512 + (k0 + tx)] = f2bf(tile[tx][i]);
  } else if (b < QB5) {
    // ---- deg_count ----
    const int e = (b - QB4) * 256 + tid;
    if (e < ETOT) {
      const int d = (e < NEDGES) ? ei[NEDGES + e] : (e - NEDGES);
      atomicAdd(&deg[d], 1);
    }
  } else {
    // ---- E1 = emb1 @ W1b ([151][512] f32) ----
    const int c = b - QB5;
#pragma unroll
    for (int jj = 0; jj < 2; ++jj) {
      const int j = tid + jj * 256;
      float a = 0.f;
      for (int k = 0; k < 200; ++k)
        a += emb1[c * 200 + k] * W1[(long)(4096 + k) * 512 + j];
      E1[c * 512 + j] = a;
    }
  }
}

// ---------------------------------------------------------------------------
// single-block exclusive scan over 20000 degrees -> off, cursor
// ---------------------------------------------------------------------------
__global__ __launch_bounds__(256) void scan_kernel(const int* __restrict__ deg,
                                                   int* __restrict__ off,
                                                   int* __restrict__ cur) {
  __shared__ int part[256];
  const int tid = threadIdx.x;
  const int chunk = (NNODES + 255) / 256;
  int start = tid * chunk;
  int end = start + chunk; if (end > NNODES) end = NNODES;
  int s = 0;
  for (int i = start; i < end; ++i) s += deg[i];
  part[tid] = s;
  __syncthreads();
  for (int d = 1; d < 256; d <<= 1) {
    const int v = (tid >= d) ? part[tid - d] : 0;
    __syncthreads();
    part[tid] += v;
    __syncthreads();
  }
  int base = part[tid] - s;   // exclusive base of this thread's chunk
  for (int i = start; i < end; ++i) { off[i] = base; cur[i] = base; base += deg[i]; }
}

__global__ void csr_fill_kernel(const int* __restrict__ ei, int* __restrict__ cur,
                                int* __restrict__ csrs) {
  const int e = blockIdx.x * 256 + threadIdx.x;
  if (e >= ETOT) return;
  const int s = (e < NEDGES) ? ei[e] : (e - NEDGES);
  const int d = (e < NEDGES) ? ei[NEDGES + e] : (e - NEDGES);
  unsigned slot = (unsigned)atomicAdd(&cur[d], 1);
  if (slot >= ETOT) slot = 0;   // hardening; never hit when deg is correct
  csrs[slot] = s;
}

// ---------------------------------------------------------------------------
// Split-K conv1 GEMM, double-buffered + counted vmcnt + T2 XOR-SWIZZLE:
// LDS slot s of row r holds global k-chunk s^((r>>1)&3). Write side stays
// linear (gld16 constraint); SOURCE global offset is pre-swizzled (m173);
// read offset sw = ((lane>>4) ^ (((lane&15)>>1)&3))*8 is constant per lane
// since (wr*64>>1)&3 = (mi*16>>1)&3 = (w*32>>1)&3 = (16>>1)&3 = 0.
// Banks: 2 lanes/bank uniform (2-way = free, m136). Was 8-way (2.94x).
// ---------------------------------------------------------------------------
__global__ __launch_bounds__(256) void gemm_split(const short* __restrict__ A,
                                                  const short* __restrict__ BT,
                                                  short* __restrict__ hp) {
  __shared__ short As[2][4096];   // [buf][128 rows][32 k]
  __shared__ short Bs[2][4096];
  const int tid = threadIdx.x;
  const int lane = tid & 63;
  const int w = tid >> 6;
  const int wr = w >> 1, wc = w & 1;
  const int wid = (blockIdx.x & 7) * 314 + ((int)blockIdx.x >> 3);
  const long bm = (long)(wid >> 4) * 128;
  const int  sk = (wid >> 2) & 3;
  const long bn = (long)(wid & 3) * 128;

  f32x4 acc[4][4] = {};

  const int ksw = ((lane & 3) ^ ((lane >> 3) & 3)) * 8;   // pre-swizzled source
  const short* gA0 = A + (bm + w * 32 + (lane >> 2)) * (long)KPADX + sk * KC + ksw;
  const short* gA1 = gA0 + 16L * KPADX;
  const short* gB0 = BT + (bn + w * 32 + (lane >> 2)) * (long)KPADX + sk * KC + ksw;
  const short* gB1 = gB0 + 16L * KPADX;

  const int lofs = w * 1024;
  const int sw = ((lane >> 4) ^ (((lane & 15) >> 1) & 3)) * 8;   // swizzled read
  const int ar = (wr * 64 + (lane & 15)) * 32 + sw;
  const int br = (wc * 64 + (lane & 15)) * 32 + sw;

  // prologue: stage tile 0 into buf 0
  gld16(gA0, &As[0][lofs]); gld16(gA1, &As[0][lofs + 512]);
  gld16(gB0, &Bs[0][lofs]); gld16(gB1, &Bs[0][lofs + 512]);
  gA0 += 32; gA1 += 32; gB0 += 32; gB1 += 32;

  const int NT = KC / 32;   // 33
  int cur = 0;
  for (int t = 0; t < NT; ++t) {
    if (t + 1 < NT) {
      gld16(gA0, &As[cur ^ 1][lofs]); gld16(gA1, &As[cur ^ 1][lofs + 512]);
      gld16(gB0, &Bs[cur ^ 1][lofs]); gld16(gB1, &Bs[cur ^ 1][lofs + 512]);
      gA0 += 32; gA1 += 32; gB0 += 32; gB1 += 32;
      asm volatile("s_waitcnt vmcnt(4)" ::: "memory");
    } else {
      asm volatile("s_waitcnt vmcnt(0)" ::: "memory");
    }
    __builtin_amdgcn_s_barrier();
    bf16x8 a[4], b[4];
#pragma unroll
    for (int mi = 0; mi < 4; ++mi) a[mi] = *(const bf16x8*)&As[cur][ar + mi * 512];
#pragma unroll
    for (int ni = 0; ni < 4; ++ni) b[ni] = *(const bf16x8*)&Bs[cur][br + ni * 512];
#pragma unroll
    for (int mi = 0; mi < 4; ++mi)
#pragma unroll
      for (int ni = 0; ni < 4; ++ni)
        acc[mi][ni] = __builtin_amdgcn_mfma_f32_16x16x32_bf16(a[mi], b[ni], acc[mi][ni], 0, 0, 0);
    __builtin_amdgcn_s_barrier();
    cur ^= 1;
  }

  short* Cp = hp + (long)sk * MPAD * 512;
#pragma unroll
  for (int mi = 0; mi < 4; ++mi) {
#pragma unroll
    for (int ni = 0; ni < 4; ++ni) {
      const long row0 = bm + wr * 64 + mi * 16 + (lane >> 4) * 4;
      const long col  = bn + wc * 64 + ni * 16 + (lane & 15);
#pragma unroll
      for (int r = 0; r < 4; ++r)
        Cp[(row0 + r) * 512 + col] = f2bf(acc[mi][ni][r]);
    }
  }
}

// ---------------------------------------------------------------------------
// reduce1: h1 = sum(hp[0..3]) + E1[label]; als/ald direct store.
// One wave per row, 4 rows/block. h1 aliases hp[0] (in-place, read-first).
// ---------------------------------------------------------------------------
__global__ __launch_bounds__(256) void reduce1_kernel(short* __restrict__ hp,
    const float* __restrict__ E1, const int* __restrict__ labels,
    const float* __restrict__ aS, const float* __restrict__ aD,
    float* __restrict__ als, float* __restrict__ ald) {
  const int row = blockIdx.x * 4 + (threadIdx.x >> 6);
  const int lane = threadIdx.x & 63;
  const int c0 = lane * 8;
  const long base = (long)row * 512 + c0;
  float v[8] = {};
#pragma unroll
  for (int s = 0; s < SK; ++s) {
    const bf16x8 p = *(const bf16x8*)&hp[(long)s * MPAD * 512 + base];
#pragma unroll
    for (int j = 0; j < 8; ++j) v[j] += bf2f(p[j]);
  }
  const int lab = (row < NNODES) ? labels[row] : 0;
  const float* e1r = E1 + (long)lab * 512;
#pragma unroll
  for (int j = 0; j < 8; ++j) v[j] += e1r[c0 + j];
  bf16x8 o;
#pragma unroll
  for (int j = 0; j < 8; ++j) o[j] = f2bf(v[j]);
  *(bf16x8*)&hp[base] = o;   // h1 = hp chunk 0 (in-place)
  float s_ = 0.f, d_ = 0.f;
#pragma unroll
  for (int j = 0; j < 8; ++j) {
    s_ += v[j] * aS[c0 + j];
    d_ += v[j] * aD[c0 + j];
  }
#pragma unroll
  for (int oo = 1; oo < 8; oo <<= 1) {
    s_ += __shfl_xor(s_, oo);
    d_ += __shfl_xor(d_, oo);
  }
  if ((lane & 7) == 0) {
    const int head = lane >> 3;
    als[row * 8 + head] = s_;
    ald[row * 8 + head] = d_;
  }
}

// ---------------------------------------------------------------------------
// conv2 GEMM, double-buffered + swizzled like gemm_split; fused als/ald.
// ---------------------------------------------------------------------------
__global__ __launch_bounds__(256) void gemm_bt(const short* __restrict__ A,
                                               const short* __restrict__ BT,
                                               short* __restrict__ C,
                                               const float* __restrict__ aS,
                                               const float* __restrict__ aD,
                                               float* __restrict__ als,
                                               float* __restrict__ ald,
                                               int Kpad, int Ncols, int H) {
  __shared__ short As[2][4096];
  __shared__ short Bs[2][4096];
  const int tid = threadIdx.x;
  const int lane = tid & 63;
  const int w = tid >> 6;
  const int wr = w >> 1, wc = w & 1;
  const int nbn = Ncols >> 7;
  const long bm = (long)((int)blockIdx.x / nbn) * 128;
  const long bn = (long)((int)blockIdx.x % nbn) * 128;

  f32x4 acc[4][4] = {};

  const int ksw = ((lane & 3) ^ ((lane >> 3) & 3)) * 8;
  const short* gA0 = A + (bm + w * 32 + (lane >> 2)) * (long)Kpad + ksw;
  const short* gA1 = gA0 + 16L * Kpad;
  const short* gB0 = BT + (bn + w * 32 + (lane >> 2)) * (long)Kpad + ksw;
  const short* gB1 = gB0 + 16L * Kpad;

  const int lofs = w * 1024;
  const int sw = ((lane >> 4) ^ (((lane & 15) >> 1) & 3)) * 8;
  const int ar = (wr * 64 + (lane & 15)) * 32 + sw;
  const int br = (wc * 64 + (lane & 15)) * 32 + sw;

  gld16(gA0, &As[0][lofs]); gld16(gA1, &As[0][lofs + 512]);
  gld16(gB0, &Bs[0][lofs]); gld16(gB1, &Bs[0][lofs + 512]);
  gA0 += 32; gA1 += 32; gB0 += 32; gB1 += 32;

  const int NT = Kpad / 32;
  int cur = 0;
  for (int t = 0; t < NT; ++t) {
    if (t + 1 < NT) {
      gld16(gA0, &As[cur ^ 1][lofs]); gld16(gA1, &As[cur ^ 1][lofs + 512]);
      gld16(gB0, &Bs[cur ^ 1][lofs]); gld16(gB1, &Bs[cur ^ 1][lofs + 512]);
      gA0 += 32; gA1 += 32; gB0 += 32; gB1 += 32;
      asm volatile("s_waitcnt vmcnt(4)" ::: "memory");
    } else {
      asm volatile("s_waitcnt vmcnt(0)" ::: "memory");
    }
    __builtin_amdgcn_s_barrier();
    bf16x8 a[4], b[4];
#pragma unroll
    for (int mi = 0; mi < 4; ++mi) a[mi] = *(const bf16x8*)&As[cur][ar + mi * 512];
#pragma unroll
    for (int ni = 0; ni < 4; ++ni) b[ni] = *(const bf16x8*)&Bs[cur][br + ni * 512];
#pragma unroll
    for (int mi = 0; mi < 4; ++mi)
#pragma unroll
      for (int ni = 0; ni < 4; ++ni)
        acc[mi][ni] = __builtin_amdgcn_mfma_f32_16x16x32_bf16(a[mi], b[ni], acc[mi][ni], 0, 0, 0);
    __builtin_amdgcn_s_barrier();
    cur ^= 1;
  }

  const int colb = (int)bn + wc * 64 + (lane & 15);

#pragma unroll
  for (int mi = 0; mi < 4; ++mi) {
#pragma unroll
    for (int ni = 0; ni < 4; ++ni) {
      const long row0 = bm + wr * 64 + mi * 16 + (lane >> 4) * 4;
      const long col  = bn + wc * 64 + ni * 16 + (lane & 15);
#pragma unroll
      for (int r = 0; r < 4; ++r)
        C[(row0 + r) * (long)Ncols + col] = f2bf(acc[mi][ni][r]);
    }
  }

  float asv[4], adv[4];
#pragma unroll
  for (int ni = 0; ni < 4; ++ni) {
    asv[ni] = aS[colb + ni * 16];
    adv[ni] = aD[colb + ni * 16];
  }
  const int head = (H == 8) ? (((int)bn >> 6) + wc) : 0;
#pragma unroll
  for (int mi = 0; mi < 4; ++mi) {
#pragma unroll
    for (int r = 0; r < 4; ++r) {
      float s = 0.f, d = 0.f;
#pragma unroll
      for (int ni = 0; ni < 4; ++ni) {
        const float v = acc[mi][ni][r];
        s += v * asv[ni];
        d += v * adv[ni];
      }
#pragma unroll
      for (int o = 1; o < 16; o <<= 1) {
        s += __shfl_xor(s, o);
        d += __shfl_xor(d, o);
      }
      if ((lane & 15) == 0) {
        const long row = bm + wr * 64 + mi * 16 + (lane >> 4) * 4 + r;
        atomicAdd(&als[row * H + head], s);
        atomicAdd(&ald[row * H + head], d);
      }
    }
  }
}

// ---------------------------------------------------------------------------
// fused per-node softmax + gather kernels
// ---------------------------------------------------------------------------
__global__ __launch_bounds__(256) void gather1_kernel(const int* __restrict__ off,
    const int* __restrict__ csrs,
    const float* __restrict__ als, const float* __restrict__ ald,
    const short* __restrict__ h1, const float* __restrict__ bias,
    short* __restrict__ ef1) {
  const int dn = blockIdx.x * 4 + (threadIdx.x >> 6);
  const int lane = threadIdx.x & 63;
  const int c0 = lane * 8;
  const int head = lane >> 3;
  const int beg = off[dn];
  const int end = (dn == NNODES - 1) ? ETOT : off[dn + 1];
  const float ad = ald[dn * 8 + head];
  float sum = 0.f;
  float acc[8] = {};
  for (int i = beg; i < end; ++i) {
    int s = csrs[i];
    if ((unsigned)s >= NNODES) s = 0;   // hardening
    float l = als[s * 8 + head] + ad;
    l = l > 0.f ? l : NSLOPE * l;
    const float wgt = expf(l);
    sum += wgt;
    const bf16x8 hv = *(const bf16x8*)&h1[(long)s * 512 + c0];
#pragma unroll
    for (int j = 0; j < 8; ++j) acc[j] += wgt * bf2f(hv[j]);
  }
  const float inv = 1.f / (sum + 1e-16f);
  bf16x8 outv;
#pragma unroll
  for (int j = 0; j < 8; ++j) {
    float r = acc[j] * inv + bias[c0 + j];
    r = r > 0.f ? r : expm1f(r);   // elu
    outv[j] = f2bf(r);
  }
  *(bf16x8*)&ef1[(long)dn * 512 + c0] = outv;
}

__global__ __launch_bounds__(256) void gather2_kernel(const int* __restrict__ off,
    const int* __restrict__ csrs,
    const float* __restrict__ als, const float* __restrict__ ald,
    const short* __restrict__ h2, const float* __restrict__ bias,
    float* __restrict__ dout) {
  const int dn = blockIdx.x * 4 + (threadIdx.x >> 6);
  const int lane = threadIdx.x & 63;
  const int c0 = lane * 8;
  const int beg = off[dn];
  const int end = (dn == NNODES - 1) ? ETOT : off[dn + 1];
  const float ad = ald[dn];
  float sum = 0.f;
  float acc[8] = {};
  for (int i = beg; i < end; ++i) {
    int s = csrs[i];
    if ((unsigned)s >= NNODES) s = 0;   // hardening
    float l = als[s] + ad;
    l = l > 0.f ? l : NSLOPE * l;
    const float wgt = expf(l);
    sum += wgt;
    const bf16x8 hv = *(const bf16x8*)&h2[(long)s * 512 + c0];
#pragma unroll
    for (int j = 0; j < 8; ++j) acc[j] += wgt * bf2f(hv[j]);
  }
  const float inv = 1.f / (sum + 1e-16f);
  float* epr = dout + OUT_EPR_OFF + (long)dn * EPRW + 4096;
  f32x4 o0, o1;
  o0.x = acc[0] * inv + bias[c0 + 0];
  o0.y = acc[1] * inv + bias[c0 + 1];
  o0.z = acc[2] * inv + bias[c0 + 2];
  o0.w = acc[3] * inv + bias[c0 + 3];
  o1.x = acc[4] * inv + bias[c0 + 4];
  o1.y = acc[5] * inv + bias[c0 + 5];
  o1.z = acc[6] * inv + bias[c0 + 6];
  o1.w = acc[7] * inv + bias[c0 + 7];
  __builtin_nontemporal_store(o0, (f32x4*)&epr[c0]);
  __builtin_nontemporal_store(o1, (f32x4*)&epr[c0 + 4]);
}

// ---------------------------------------------------------------------------
extern "C" void kernel_launch(void* const* d_in, const int* in_sizes, int n_in,
                              void* d_out, int out_size, void* d_ws, size_t ws_size,
                              hipStream_t stream) {
  const float* roi  = (const float*)d_in[0];
  const float* box  = (const float*)d_in[1];
  const float* emb1 = (const float*)d_in[2];
  const float* emb2 = (const float*)d_in[3];
  const float* bw1  = (const float*)d_in[4];
  const float* bb1  = (const float*)d_in[5];
  const float* bw2  = (const float*)d_in[6];
  const float* bb2  = (const float*)d_in[7];
  const float* W1   = (const float*)d_in[8];
  const float* as1  = (const float*)d_in[9];
  const float* ad1  = (const float*)d_in[10];
  const float* b1   = (const float*)d_in[11];
  const float* W2   = (const float*)d_in[12];
  const float* as2  = (const float*)d_in[13];
  const float* ad2  = (const float*)d_in[14];
  const float* b2   = (const float*)d_in[15];
  const int* labels = (const int*)d_in[16];
  const int* ei     = (const int*)d_in[17];
  float* dout = (float*)d_out;

  char* wsb = (char*)d_ws;
  size_t o = 0;
  auto alloc = [&](size_t bytes) -> void* {
    void* p = wsb + o;
    o += (bytes + 255) & ~(size_t)255;
    return p;
  };
  short* x    = (short*)alloc((size_t)MPAD * KPADX * 2);       // bf16 [MPAD][4224]
  short* w1t  = (short*)alloc((size_t)512 * KPADX * 2);        // bf16 [512][4224]
  short* hp   = (short*)alloc((size_t)SK * MPAD * 512 * 2);    // bf16 partials; h1 = chunk 0
  short* h1   = hp;
  short* ef1  = (short*)alloc((size_t)MPAD * 512 * 2);         // bf16
  short* w2t  = (short*)alloc((size_t)512 * 512 * 2);
  short* h2   = (short*)alloc((size_t)MPAD * 512 * 2);         // bf16
  float* als1 = (float*)alloc((size_t)MPAD * 8 * 4);
  float* ald1 = (float*)alloc((size_t)MPAD * 8 * 4);
  float* als2 = (float*)alloc((size_t)MPAD * 4);
  float* ald2 = (float*)alloc((size_t)MPAD * 4);
  float* E1   = (float*)alloc((size_t)NCLS * 512 * 4);
  int*   deg  = (int*)alloc((size_t)NNODES * 4);
  int*   offs = (int*)alloc((size_t)NNODES * 4);
  int*   cur  = (int*)alloc((size_t)NNODES * 4);
  int*   csrs = (int*)alloc((size_t)ETOT * 4);

  const int EB = (ETOT + 255) / 256;   // 1329

  hipMemsetAsync(deg, 0, (size_t)NNODES * 4, stream);

  hipLaunchKernelGGL(mega_prep_kernel, dim3(QB6), dim3(256), 0, stream,
                     roi, box, emb1, emb2, bw1, bb1, bw2, bb2, W1, W2,
                     labels, ei, x, w1t, w2t, ef1, deg,
                     als2, ald2, E1, dout);
  hipLaunchKernelGGL(scan_kernel, dim3(1), dim3(256), 0, stream, deg, offs, cur);
  hipLaunchKernelGGL(csr_fill_kernel, dim3(EB), dim3(256), 0, stream, ei, cur, csrs);
  // conv1: split-K GEMM -> partials, then reduce (+E1, +als/ald)
  hipLaunchKernelGGL(gemm_split, dim3(157 * SK * 4), dim3(256), 0, stream,
                     x, w1t, hp);
  hipLaunchKernelGGL(reduce1_kernel, dim3(MPAD / 4), dim3(256), 0, stream,
                     hp, E1, labels, as1, ad1, als1, ald1);
  hipLaunchKernelGGL(gather1_kernel, dim3(NNODES / 4), dim3(256), 0, stream,
                     offs, csrs, als1, ald1, h1, b1, ef1);
  // conv2 GEMM (+fused als/ald)
  hipLaunchKernelGGL(gemm_bt, dim3(157 * 4), dim3(256), 0, stream,
                     ef1, w2t, h2, as2, ad2, als2, ald2, 512, 512, 1);
  hipLaunchKernelGGL(gather2_kernel, dim3(NNODES / 4), dim3(256), 0, stream,
                     offs, csrs, als2, ald2, h2, b2, dout);
}

// Round 14
// 546.620 us; speedup vs baseline: 1.1365x; 1.0567x over previous
//
#include <hip/hip_runtime.h>
#include <hip/hip_bf16.h>

#define NNODES 20000
#define NEDGES 320000
#define ETOT   (NEDGES + NNODES)   // 340000, self-loops appended after edges
#define KPADX  4224                // 4096 roi + 128 pos (emb1 handled via E1 table)
#define SK     2                   // K-splits for conv1 GEMM
#define KC     (KPADX / SK)        // 2112 = 66*32
#define NGEMM1 (157 * SK * 4)      // 1256
#define EB     ((ETOT + 255) / 256) // 1329 csr_fill tail blocks
#define MPAD   20096               // 157*128
#define NCLS   151
#define EPRW   4808                // 4096 + 512 + 200
#define OUT_LAB_OFF  3020000L      // N*151
#define OUT_EPR_OFF  3040000L      // N*151 + N
#define NSLOPE 0.2f

typedef __attribute__((ext_vector_type(8))) short bf16x8;
typedef __attribute__((ext_vector_type(4))) float f32x4;
typedef __attribute__((ext_vector_type(4))) short s16x4;

__device__ __forceinline__ short f2bf(float v) {
  union { __hip_bfloat16 b; short s; } u;
  u.b = __float2bfloat16(v);
  return u.s;
}

__device__ __forceinline__ float bf2f(short s) {
  union { float f; unsigned u; } x;
  x.u = ((unsigned)(unsigned short)s) << 16;
  return x.f;
}

__device__ __forceinline__ void gld16(const short* g, short* l) {
  __builtin_amdgcn_global_load_lds(
      (const __attribute__((address_space(1))) unsigned int*)g,
      (__attribute__((address_space(3))) unsigned int*)l, 16, 0, 0);
}

// ---------------------------------------------------------------------------
// mega-prep block ranges (r10-proven structure: single roi read, dual store):
//  [0, 10000)   ROI COPY: roi -> epr (f32 NT) + x (bf16), 8 indep 16B chunks/thr
//  [.., +5000)  MLP/emb2/one-hot/label: 4 nodes/block, 1 wave/node
//  [.., +1584)  zero init: x/ef1 pad rows, als2/ald2
//  [.., +2112)  transpose W1 -> w1t bf16 [512][4224] (skip emb1 rows)
//  [.., +256)   transpose W2 -> w2t bf16 [512][512]
//  [.., +1329)  deg_count (deg pre-zeroed via hipMemsetAsync)
//  [.., +151)   E1[c] = emb1[c] @ W1b (f32 [151][512])
// ---------------------------------------------------------------------------
#define QB0 10000
#define QB1 (QB0 + 5000)
#define QB2 (QB1 + 1584)
#define QB3 (QB2 + 2112)
#define QB4 (QB3 + 256)
#define QB5 (QB4 + 1329)
#define QB6 (QB5 + 151)

__global__ __launch_bounds__(256) void mega_prep_kernel(
    const float* __restrict__ roi, const float* __restrict__ box,
    const float* __restrict__ emb1, const float* __restrict__ emb2,
    const float* __restrict__ bw1, const float* __restrict__ bb1,
    const float* __restrict__ bw2, const float* __restrict__ bb2,
    const float* __restrict__ W1, const float* __restrict__ W2,
    const int* __restrict__ labels, const int* __restrict__ ei,
    short* __restrict__ x, short* __restrict__ w1t, short* __restrict__ w2t,
    short* __restrict__ ef1, int* __restrict__ deg,
    float* __restrict__ als2, float* __restrict__ ald2,
    float* __restrict__ E1, float* __restrict__ dout) {
  const int b = blockIdx.x;
  const int tid = threadIdx.x;

  __shared__ float hids[4][32];
  __shared__ float tile[32][33];

  if (b < QB0) {
    // ---- roi streaming copy: 2048 chunks/block, 8/thread, no barriers ----
    const int base = b * 2048 + tid;
    f32x4 v[8];
#pragma unroll
    for (int k = 0; k < 8; ++k)
      v[k] = *(const f32x4*)&roi[(long)(base + k * 256) * 4];
#pragma unroll
    for (int k = 0; k < 8; ++k) {
      const int t = base + k * 256;
      const int node = t >> 10, cq = t & 1023;
      __builtin_nontemporal_store(v[k],
          (f32x4*)&dout[OUT_EPR_OFF + (long)node * EPRW + cq * 4]);
      s16x4 bb;
      bb.x = f2bf(v[k].x); bb.y = f2bf(v[k].y);
      bb.z = f2bf(v[k].z); bb.w = f2bf(v[k].w);
      *(s16x4*)&x[(long)node * KPADX + cq * 4] = bb;
    }
  } else if (b < QB1) {
    // ---- MLP + emb2 + one-hot + label: 4 nodes/block, wave per node ----
    const int w = tid >> 6;
    const int lane = tid & 63;
    const int nd = (b - QB0) * 4 + w;
    if (lane < 32) {
      float a = bb1[lane];
#pragma unroll
      for (int i = 0; i < 9; ++i) a += box[nd * 9 + i] * bw1[i * 32 + lane];
      hids[w][lane] = a > 0.f ? a : 0.f;
    }
    __syncthreads();
    const long xrow = (long)nd * KPADX;
#pragma unroll
    for (int jj = 0; jj < 2; ++jj) {
      const int j = lane + jj * 64;
      float a = bb2[j];
#pragma unroll
      for (int i = 0; i < 32; ++i) a += hids[w][i] * bw2[i * 128 + j];
      a = a > 0.f ? a : 0.f;
      x[xrow + 4096 + j] = f2bf(a);      // pos (x cols 4096..4223)
    }
    const int lab = labels[nd];
    float* epr = dout + OUT_EPR_OFF + (long)nd * EPRW;
    if (lane < 50) {
      const f32x4 e2 = *(const f32x4*)&emb2[lab * 200 + lane * 4];
      __builtin_nontemporal_store(e2, (f32x4*)&epr[4608 + lane * 4]);
    }
    for (int j = lane; j < NCLS; j += 64)
      dout[(long)nd * NCLS + j] = (j == lab) ? 1.f : 0.f;
    if (lane == 0) dout[OUT_LAB_OFF + nd] = (float)lab;
  } else if (b < QB2) {
    // ---- zero init ----
    const int t = (b - QB1) * 256 + tid;
    if (t < 96 * KPADX) x[(long)NNODES * KPADX + t] = 0;
    if (t < 96 * 512)   ef1[(long)NNODES * 512 + t] = 0;
    if (t < MPAD)       { als2[t] = 0.f; ald2[t] = 0.f; }
  } else if (b < QB3) {
    // ---- transpose W1 (4424x512 -> [512][4224], skipping emb rows) ----
    const int t = b - QB2;
    const int n0 = (t % 16) * 32;
    const int k0 = (t / 16) * 32;
    const int tx = tid & 31, ty = tid >> 5;
#pragma unroll
    for (int i = ty; i < 32; i += 8) {
      const int kp = k0 + i;
      const int src = kp < 4096 ? kp : kp + 200;
      tile[i][tx] = W1[(long)src * 512 + (n0 + tx)];
    }
    __syncthreads();
#pragma unroll
    for (int i = ty; i < 32; i += 8)
      w1t[(long)(n0 + i) * KPADX + (k0 + tx)] = f2bf(tile[tx][i]);
  } else if (b < QB4) {
    // ---- transpose W2 (512x512) ----
    const int t = b - QB3;
    const int n0 = (t % 16) * 32;
    const int k0 = (t / 16) * 32;
    const int tx = tid & 31, ty = tid >> 5;
#pragma unroll
    for (int i = ty; i < 32; i += 8)
      tile[i][tx] = W2[(long)(k0 + i) * 512 + (n0 + tx)];
    __syncthreads();
#pragma unroll
    for (int i = ty; i < 32; i += 8)
      w2t[(long)(n0 + i) * 512 + (k0 + tx)] = f2bf(tile[tx][i]);
  } else if (b < QB5) {
    // ---- deg_count ----
    const int e = (b - QB4) * 256 + tid;
    if (e < ETOT) {
      const int d = (e < NEDGES) ? ei[NEDGES + e] : (e - NEDGES);
      atomicAdd(&deg[d], 1);
    }
  } else {
    // ---- E1 = emb1 @ W1b ([151][512] f32) ----
    const int c = b - QB5;
#pragma unroll
    for (int jj = 0; jj < 2; ++jj) {
      const int j = tid + jj * 256;
      float a = 0.f;
      for (int k = 0; k < 200; ++k)
        a += emb1[c * 200 + k] * W1[(long)(4096 + k) * 512 + j];
      E1[c * 512 + j] = a;
    }
  }
}

// ---------------------------------------------------------------------------
// single-block exclusive scan over 20000 degrees -> off, cursor
// ---------------------------------------------------------------------------
__global__ __launch_bounds__(256) void scan_kernel(const int* __restrict__ deg,
                                                   int* __restrict__ off,
                                                   int* __restrict__ cur) {
  __shared__ int part[256];
  const int tid = threadIdx.x;
  const int chunk = (NNODES + 255) / 256;
  int start = tid * chunk;
  int end = start + chunk; if (end > NNODES) end = NNODES;
  int s = 0;
  for (int i = start; i < end; ++i) s += deg[i];
  part[tid] = s;
  __syncthreads();
  for (int d = 1; d < 256; d <<= 1) {
    const int v = (tid >= d) ? part[tid - d] : 0;
    __syncthreads();
    part[tid] += v;
    __syncthreads();
  }
  int base = part[tid] - s;   // exclusive base of this thread's chunk
  for (int i = start; i < end; ++i) { off[i] = base; cur[i] = base; base += deg[i]; }
}

// ---------------------------------------------------------------------------
// Split-K conv1 GEMM (SK=2), double-buffered + counted vmcnt; csr_fill rides
// in tail blocks [NGEMM1, NGEMM1+EB) — atomics hide under GEMM compute.
// GEMM decode XCD-grouped: wid=(bid&7)*157+(bid>>3); bm=wid>>3, sk=(wid>>2)&1,
// bn=wid&3 — the 4 bn-sharers of one (bm,sk) A-chunk are wid-consecutive on
// one XCD (L2 reuse).
// ---------------------------------------------------------------------------
__global__ __launch_bounds__(256) void gemm_split(const short* __restrict__ A,
                                                  const short* __restrict__ BT,
                                                  short* __restrict__ hp,
                                                  const int* __restrict__ ei,
                                                  int* __restrict__ cur_,
                                                  int* __restrict__ csrs) {
  const int tid = threadIdx.x;
  if ((int)blockIdx.x >= NGEMM1) {
    // ---- csr_fill tail ----
    const int e = ((int)blockIdx.x - NGEMM1) * 256 + tid;
    if (e < ETOT) {
      const int s = (e < NEDGES) ? ei[e] : (e - NEDGES);
      const int d = (e < NEDGES) ? ei[NEDGES + e] : (e - NEDGES);
      unsigned slot = (unsigned)atomicAdd(&cur_[d], 1);
      if (slot >= ETOT) slot = 0;   // hardening; never hit when deg is correct
      csrs[slot] = s;
    }
    return;
  }
  __shared__ short As[2][4096];   // [buf][128 rows][32 k]
  __shared__ short Bs[2][4096];
  const int lane = tid & 63;
  const int w = tid >> 6;
  const int wr = w >> 1, wc = w & 1;
  const int wid = (blockIdx.x & 7) * 157 + ((int)blockIdx.x >> 3);
  const long bm = (long)(wid >> 3) * 128;
  const int  sk = (wid >> 2) & 1;
  const long bn = (long)(wid & 3) * 128;

  f32x4 acc[4][4] = {};

  const short* gA0 = A + (bm + w * 32 + (lane >> 2)) * (long)KPADX + sk * KC + (lane & 3) * 8;
  const short* gA1 = gA0 + 16L * KPADX;
  const short* gB0 = BT + (bn + w * 32 + (lane >> 2)) * (long)KPADX + sk * KC + (lane & 3) * 8;
  const short* gB1 = gB0 + 16L * KPADX;

  const int lofs = w * 1024;
  const int ar = (wr * 64 + (lane & 15)) * 32 + (lane >> 4) * 8;
  const int br = (wc * 64 + (lane & 15)) * 32 + (lane >> 4) * 8;

  // prologue: stage tile 0 into buf 0
  gld16(gA0, &As[0][lofs]); gld16(gA1, &As[0][lofs + 512]);
  gld16(gB0, &Bs[0][lofs]); gld16(gB1, &Bs[0][lofs + 512]);
  gA0 += 32; gA1 += 32; gB0 += 32; gB1 += 32;

  const int NT = KC / 32;   // 66
  int cur = 0;
  for (int t = 0; t < NT; ++t) {
    if (t + 1 < NT) {
      gld16(gA0, &As[cur ^ 1][lofs]); gld16(gA1, &As[cur ^ 1][lofs + 512]);
      gld16(gB0, &Bs[cur ^ 1][lofs]); gld16(gB1, &Bs[cur ^ 1][lofs + 512]);
      gA0 += 32; gA1 += 32; gB0 += 32; gB1 += 32;
      asm volatile("s_waitcnt vmcnt(4)" ::: "memory");
    } else {
      asm volatile("s_waitcnt vmcnt(0)" ::: "memory");
    }
    __builtin_amdgcn_s_barrier();
    bf16x8 a[4], b[4];
#pragma unroll
    for (int mi = 0; mi < 4; ++mi) a[mi] = *(const bf16x8*)&As[cur][ar + mi * 512];
#pragma unroll
    for (int ni = 0; ni < 4; ++ni) b[ni] = *(const bf16x8*)&Bs[cur][br + ni * 512];
#pragma unroll
    for (int mi = 0; mi < 4; ++mi)
#pragma unroll
      for (int ni = 0; ni < 4; ++ni)
        acc[mi][ni] = __builtin_amdgcn_mfma_f32_16x16x32_bf16(a[mi], b[ni], acc[mi][ni], 0, 0, 0);
    __builtin_amdgcn_s_barrier();
    cur ^= 1;
  }

  short* Cp = hp + (long)sk * MPAD * 512;
#pragma unroll
  for (int mi = 0; mi < 4; ++mi) {
#pragma unroll
    for (int ni = 0; ni < 4; ++ni) {
      const long row0 = bm + wr * 64 + mi * 16 + (lane >> 4) * 4;
      const long col  = bn + wc * 64 + ni * 16 + (lane & 15);
#pragma unroll
      for (int r = 0; r < 4; ++r)
        Cp[(row0 + r) * 512 + col] = f2bf(acc[mi][ni][r]);
    }
  }
}

// ---------------------------------------------------------------------------
// reduce1: h1 = sum(hp[0..SK)) + E1[label]; als/ald direct store.
// One wave per row, 4 rows/block. h1 aliases hp[0] (in-place, read-first).
// ---------------------------------------------------------------------------
__global__ __launch_bounds__(256) void reduce1_kernel(short* __restrict__ hp,
    const float* __restrict__ E1, const int* __restrict__ labels,
    const float* __restrict__ aS, const float* __restrict__ aD,
    float* __restrict__ als, float* __restrict__ ald) {
  const int row = blockIdx.x * 4 + (threadIdx.x >> 6);
  const int lane = threadIdx.x & 63;
  const int c0 = lane * 8;
  const long base = (long)row * 512 + c0;
  float v[8] = {};
#pragma unroll
  for (int s = 0; s < SK; ++s) {
    const bf16x8 p = *(const bf16x8*)&hp[(long)s * MPAD * 512 + base];
#pragma unroll
    for (int j = 0; j < 8; ++j) v[j] += bf2f(p[j]);
  }
  const int lab = (row < NNODES) ? labels[row] : 0;
  const float* e1r = E1 + (long)lab * 512;
#pragma unroll
  for (int j = 0; j < 8; ++j) v[j] += e1r[c0 + j];
  bf16x8 o;
#pragma unroll
  for (int j = 0; j < 8; ++j) o[j] = f2bf(v[j]);
  *(bf16x8*)&hp[base] = o;   // h1 = hp chunk 0 (in-place)
  float s_ = 0.f, d_ = 0.f;
#pragma unroll
  for (int j = 0; j < 8; ++j) {
    s_ += v[j] * aS[c0 + j];
    d_ += v[j] * aD[c0 + j];
  }
#pragma unroll
  for (int oo = 1; oo < 8; oo <<= 1) {
    s_ += __shfl_xor(s_, oo);
    d_ += __shfl_xor(d_, oo);
  }
  if ((lane & 7) == 0) {
    const int head = lane >> 3;
    als[row * 8 + head] = s_;
    ald[row * 8 + head] = d_;
  }
}

// ---------------------------------------------------------------------------
// conv2 GEMM, double-buffered; fused als/ald epilogue (atomics).
// ---------------------------------------------------------------------------
__global__ __launch_bounds__(256) void gemm_bt(const short* __restrict__ A,
                                               const short* __restrict__ BT,
                                               short* __restrict__ C,
                                               const float* __restrict__ aS,
                                               const float* __restrict__ aD,
                                               float* __restrict__ als,
                                               float* __restrict__ ald,
                                               int Kpad, int Ncols, int H) {
  __shared__ short As[2][4096];
  __shared__ short Bs[2][4096];
  const int tid = threadIdx.x;
  const int lane = tid & 63;
  const int w = tid >> 6;
  const int wr = w >> 1, wc = w & 1;
  const int nbn = Ncols >> 7;
  const long bm = (long)((int)blockIdx.x / nbn) * 128;
  const long bn = (long)((int)blockIdx.x % nbn) * 128;

  f32x4 acc[4][4] = {};

  const short* gA0 = A + (bm + w * 32 + (lane >> 2)) * (long)Kpad + (lane & 3) * 8;
  const short* gA1 = gA0 + 16L * Kpad;
  const short* gB0 = BT + (bn + w * 32 + (lane >> 2)) * (long)Kpad + (lane & 3) * 8;
  const short* gB1 = gB0 + 16L * Kpad;

  const int lofs = w * 1024;
  const int ar = (wr * 64 + (lane & 15)) * 32 + (lane >> 4) * 8;
  const int br = (wc * 64 + (lane & 15)) * 32 + (lane >> 4) * 8;

  gld16(gA0, &As[0][lofs]); gld16(gA1, &As[0][lofs + 512]);
  gld16(gB0, &Bs[0][lofs]); gld16(gB1, &Bs[0][lofs + 512]);
  gA0 += 32; gA1 += 32; gB0 += 32; gB1 += 32;

  const int NT = Kpad / 32;
  int cur = 0;
  for (int t = 0; t < NT; ++t) {
    if (t + 1 < NT) {
      gld16(gA0, &As[cur ^ 1][lofs]); gld16(gA1, &As[cur ^ 1][lofs + 512]);
      gld16(gB0, &Bs[cur ^ 1][lofs]); gld16(gB1, &Bs[cur ^ 1][lofs + 512]);
      gA0 += 32; gA1 += 32; gB0 += 32; gB1 += 32;
      asm volatile("s_waitcnt vmcnt(4)" ::: "memory");
    } else {
      asm volatile("s_waitcnt vmcnt(0)" ::: "memory");
    }
    __builtin_amdgcn_s_barrier();
    bf16x8 a[4], b[4];
#pragma unroll
    for (int mi = 0; mi < 4; ++mi) a[mi] = *(const bf16x8*)&As[cur][ar + mi * 512];
#pragma unroll
    for (int ni = 0; ni < 4; ++ni) b[ni] = *(const bf16x8*)&Bs[cur][br + ni * 512];
#pragma unroll
    for (int mi = 0; mi < 4; ++mi)
#pragma unroll
      for (int ni = 0; ni < 4; ++ni)
        acc[mi][ni] = __builtin_amdgcn_mfma_f32_16x16x32_bf16(a[mi], b[ni], acc[mi][ni], 0, 0, 0);
    __builtin_amdgcn_s_barrier();
    cur ^= 1;
  }

  const int colb = (int)bn + wc * 64 + (lane & 15);

#pragma unroll
  for (int mi = 0; mi < 4; ++mi) {
#pragma unroll
    for (int ni = 0; ni < 4; ++ni) {
      const long row0 = bm + wr * 64 + mi * 16 + (lane >> 4) * 4;
      const long col  = bn + wc * 64 + ni * 16 + (lane & 15);
#pragma unroll
      for (int r = 0; r < 4; ++r)
        C[(row0 + r) * (long)Ncols + col] = f2bf(acc[mi][ni][r]);
    }
  }

  float asv[4], adv[4];
#pragma unroll
  for (int ni = 0; ni < 4; ++ni) {
    asv[ni] = aS[colb + ni * 16];
    adv[ni] = aD[colb + ni * 16];
  }
  const int head = (H == 8) ? (((int)bn >> 6) + wc) : 0;
#pragma unroll
  for (int mi = 0; mi < 4; ++mi) {
#pragma unroll
    for (int r = 0; r < 4; ++r) {
      float s = 0.f, d = 0.f;
#pragma unroll
      for (int ni = 0; ni < 4; ++ni) {
        const float v = acc[mi][ni][r];
        s += v * asv[ni];
        d += v * adv[ni];
      }
#pragma unroll
      for (int o = 1; o < 16; o <<= 1) {
        s += __shfl_xor(s, o);
        d += __shfl_xor(d, o);
      }
      if ((lane & 15) == 0) {
        const long row = bm + wr * 64 + mi * 16 + (lane >> 4) * 4 + r;
        atomicAdd(&als[row * H + head], s);
        atomicAdd(&ald[row * H + head], d);
      }
    }
  }
}

// ---------------------------------------------------------------------------
// fused per-node softmax + gather kernels
// ---------------------------------------------------------------------------
__global__ __launch_bounds__(256) void gather1_kernel(const int* __restrict__ off,
    const int* __restrict__ csrs,
    const float* __restrict__ als, const float* __restrict__ ald,
    const short* __restrict__ h1, const float* __restrict__ bias,
    short* __restrict__ ef1) {
  const int dn = blockIdx.x * 4 + (threadIdx.x >> 6);
  const int lane = threadIdx.x & 63;
  const int c0 = lane * 8;
  const int head = lane >> 3;
  const int beg = off[dn];
  const int end = (dn == NNODES - 1) ? ETOT : off[dn + 1];
  const float ad = ald[dn * 8 + head];
  float sum = 0.f;
  float acc[8] = {};
  for (int i = beg; i < end; ++i) {
    int s = csrs[i];
    if ((unsigned)s >= NNODES) s = 0;   // hardening
    float l = als[s * 8 + head] + ad;
    l = l > 0.f ? l : NSLOPE * l;
    const float wgt = expf(l);
    sum += wgt;
    const bf16x8 hv = *(const bf16x8*)&h1[(long)s * 512 + c0];
#pragma unroll
    for (int j = 0; j < 8; ++j) acc[j] += wgt * bf2f(hv[j]);
  }
  const float inv = 1.f / (sum + 1e-16f);
  bf16x8 outv;
#pragma unroll
  for (int j = 0; j < 8; ++j) {
    float r = acc[j] * inv + bias[c0 + j];
    r = r > 0.f ? r : expm1f(r);   // elu
    outv[j] = f2bf(r);
  }
  *(bf16x8*)&ef1[(long)dn * 512 + c0] = outv;
}

__global__ __launch_bounds__(256) void gather2_kernel(const int* __restrict__ off,
    const int* __restrict__ csrs,
    const float* __restrict__ als, const float* __restrict__ ald,
    const short* __restrict__ h2, const float* __restrict__ bias,
    float* __restrict__ dout) {
  const int dn = blockIdx.x * 4 + (threadIdx.x >> 6);
  const int lane = threadIdx.x & 63;
  const int c0 = lane * 8;
  const int beg = off[dn];
  const int end = (dn == NNODES - 1) ? ETOT : off[dn + 1];
  const float ad = ald[dn];
  float sum = 0.f;
  float acc[8] = {};
  for (int i = beg; i < end; ++i) {
    int s = csrs[i];
    if ((unsigned)s >= NNODES) s = 0;   // hardening
    float l = als[s] + ad;
    l = l > 0.f ? l : NSLOPE * l;
    const float wgt = expf(l);
    sum += wgt;
    const bf16x8 hv = *(const bf16x8*)&h2[(long)s * 512 + c0];
#pragma unroll
    for (int j = 0; j < 8; ++j) acc[j] += wgt * bf2f(hv[j]);
  }
  const float inv = 1.f / (sum + 1e-16f);
  float* epr = dout + OUT_EPR_OFF + (long)dn * EPRW + 4096;
  f32x4 o0, o1;
  o0.x = acc[0] * inv + bias[c0 + 0];
  o0.y = acc[1] * inv + bias[c0 + 1];
  o0.z = acc[2] * inv + bias[c0 + 2];
  o0.w = acc[3] * inv + bias[c0 + 3];
  o1.x = acc[4] * inv + bias[c0 + 4];
  o1.y = acc[5] * inv + bias[c0 + 5];
  o1.z = acc[6] * inv + bias[c0 + 6];
  o1.w = acc[7] * inv + bias[c0 + 7];
  __builtin_nontemporal_store(o0, (f32x4*)&epr[c0]);
  __builtin_nontemporal_store(o1, (f32x4*)&epr[c0 + 4]);
}

// ---------------------------------------------------------------------------
extern "C" void kernel_launch(void* const* d_in, const int* in_sizes, int n_in,
                              void* d_out, int out_size, void* d_ws, size_t ws_size,
                              hipStream_t stream) {
  const float* roi  = (const float*)d_in[0];
  const float* box  = (const float*)d_in[1];
  const float* emb1 = (const float*)d_in[2];
  const float* emb2 = (const float*)d_in[3];
  const float* bw1  = (const float*)d_in[4];
  const float* bb1  = (const float*)d_in[5];
  const float* bw2  = (const float*)d_in[6];
  const float* bb2  = (const float*)d_in[7];
  const float* W1   = (const float*)d_in[8];
  const float* as1  = (const float*)d_in[9];
  const float* ad1  = (const float*)d_in[10];
  const float* b1   = (const float*)d_in[11];
  const float* W2   = (const float*)d_in[12];
  const float* as2  = (const float*)d_in[13];
  const float* ad2  = (const float*)d_in[14];
  const float* b2   = (const float*)d_in[15];
  const int* labels = (const int*)d_in[16];
  const int* ei     = (const int*)d_in[17];
  float* dout = (float*)d_out;

  char* wsb = (char*)d_ws;
  size_t o = 0;
  auto alloc = [&](size_t bytes) -> void* {
    void* p = wsb + o;
    o += (bytes + 255) & ~(size_t)255;
    return p;
  };
  short* x    = (short*)alloc((size_t)MPAD * KPADX * 2);       // bf16 [MPAD][4224]
  short* w1t  = (short*)alloc((size_t)512 * KPADX * 2);        // bf16 [512][4224]
  short* hp   = (short*)alloc((size_t)SK * MPAD * 512 * 2);    // bf16 partials; h1 = chunk 0
  short* h1   = hp;
  short* ef1  = (short*)alloc((size_t)MPAD * 512 * 2);         // bf16
  short* w2t  = (short*)alloc((size_t)512 * 512 * 2);
  short* h2   = (short*)alloc((size_t)MPAD * 512 * 2);         // bf16
  float* als1 = (float*)alloc((size_t)MPAD * 8 * 4);
  float* ald1 = (float*)alloc((size_t)MPAD * 8 * 4);
  float* als2 = (float*)alloc((size_t)MPAD * 4);
  float* ald2 = (float*)alloc((size_t)MPAD * 4);
  float* E1   = (float*)alloc((size_t)NCLS * 512 * 4);
  int*   deg  = (int*)alloc((size_t)NNODES * 4);
  int*   offs = (int*)alloc((size_t)NNODES * 4);
  int*   cur  = (int*)alloc((size_t)NNODES * 4);
  int*   csrs = (int*)alloc((size_t)ETOT * 4);

  hipMemsetAsync(deg, 0, (size_t)NNODES * 4, stream);

  hipLaunchKernelGGL(mega_prep_kernel, dim3(QB6), dim3(256), 0, stream,
                     roi, box, emb1, emb2, bw1, bb1, bw2, bb2, W1, W2,
                     labels, ei, x, w1t, w2t, ef1, deg,
                     als2, ald2, E1, dout);
  hipLaunchKernelGGL(scan_kernel, dim3(1), dim3(256), 0, stream, deg, offs, cur);
  // conv1: split-K GEMM (+csr_fill tail) -> partials, then reduce (+E1, +als/ald)
  hipLaunchKernelGGL(gemm_split, dim3(NGEMM1 + EB), dim3(256), 0, stream,
                     x, w1t, hp, ei, cur, csrs);
  hipLaunchKernelGGL(reduce1_kernel, dim3(MPAD / 4), dim3(256), 0, stream,
                     hp, E1, labels, as1, ad1, als1, ald1);
  hipLaunchKernelGGL(gather1_kernel, dim3(NNODES / 4), dim3(256), 0, stream,
                     offs, csrs, als1, ald1, h1, b1, ef1);
  // conv2 GEMM (+fused als/ald)
  hipLaunchKernelGGL(gemm_bt, dim3(157 * 4), dim3(256), 0, stream,
                     ef1, w2t, h2, as2, ad2, als2, ald2, 512, 512, 1);
  hipLaunchKernelGGL(gather2_kernel, dim3(NNODES / 4), dim3(256), 0, stream,
                     offs, csrs, als2, ald2, h2, b2, dout);
}